// Round 1
// baseline (463.638 us; speedup 1.0000x reference)
//
#include <hip/hip_runtime.h>
#include <math.h>

// Problem constants (match reference)
constexpr int kVerts = 5000;
constexpr int kFaces = 10000;
constexpr int kPts   = 16384;   // BATCH * N_PTS = 2 * 8192
constexpr int kOuter = 4;
constexpr int kInner = 50;

#define SCALE 10.0f

// ---------------------------------------------------------------------------
// Kernel 1: KNN (K=1) of query points against triangle centers.
// grid 256 x block 256. Each block handles 64 points; threads are organized as
// (partition = tid>>6) x (lane = tid&63). Each partition scans 1/4 of each
// 512-face tile staged in LDS (centers recomputed per block -- inputs are tiny
// and L2-resident, avoids d_ws). Wave-uniform tile reads -> LDS broadcast.
//
// All arithmetic uses explicit *_rn intrinsics to forbid fma contraction,
// replicating plain per-op IEEE fp32 (best match to XLA's lowering) so that
// argmin near-ties resolve identically to the reference.
// ---------------------------------------------------------------------------
#define KNN_TILE 512

__global__ __launch_bounds__(256)
void knn_kernel(const float* __restrict__ verts,
                const float* __restrict__ mesh_V,
                const int*   __restrict__ mesh_F,
                float*       __restrict__ out)
{
    __shared__ float4 s_cent[KNN_TILE];
    __shared__ float  s_best[256];
    __shared__ int    s_bestf[256];

    const int tid  = threadIdx.x;
    const int lane = tid & 63;
    const int part = tid >> 6;              // 0..3
    const int p    = blockIdx.x * 64 + lane;

    const float qx = verts[p * 3 + 0];
    const float qy = verts[p * 3 + 1];
    const float qz = verts[p * 3 + 2];
    // (verts**2).sum(-1): (x^2 + y^2) + z^2, plain ops
    const float q2 = __fadd_rn(__fadd_rn(__fmul_rn(qx, qx), __fmul_rn(qy, qy)),
                               __fmul_rn(qz, qz));

    float best  = INFINITY;
    int   bestf = 0x7fffffff;

    for (int base = 0; base < kFaces; base += KNN_TILE) {
        const int cnt = min(KNN_TILE, kFaces - base);
        __syncthreads();   // protect previous tile's readers
        for (int i = tid; i < cnt; i += 256) {
            const int f  = base + i;
            const int i0 = mesh_F[f * 3 + 0];
            const int i1 = mesh_F[f * 3 + 1];
            const int i2 = mesh_F[f * 3 + 2];
            // mean over the 3 vertices: ((V0+V1)+V2)/3, true division
            const float cx = __fdiv_rn(__fadd_rn(__fadd_rn(mesh_V[i0*3+0], mesh_V[i1*3+0]), mesh_V[i2*3+0]), 3.0f);
            const float cy = __fdiv_rn(__fadd_rn(__fadd_rn(mesh_V[i0*3+1], mesh_V[i1*3+1]), mesh_V[i2*3+1]), 3.0f);
            const float cz = __fdiv_rn(__fadd_rn(__fadd_rn(mesh_V[i0*3+2], mesh_V[i1*3+2]), mesh_V[i2*3+2]), 3.0f);
            const float cc = __fadd_rn(__fadd_rn(__fmul_rn(cx, cx), __fmul_rn(cy, cy)),
                                       __fmul_rn(cz, cz));
            s_cent[i] = make_float4(cx, cy, cz, cc);
        }
        __syncthreads();
        const int jbeg = part * (KNN_TILE / 4);
        const int jend = min(jbeg + (KNN_TILE / 4), cnt);
        for (int j = jbeg; j < jend; ++j) {
            const float4 c = s_cent[j];   // wave-uniform address -> broadcast
            // dot = ((qx*cx + qy*cy) + qz*cz), plain ops, left-to-right
            const float dot = __fadd_rn(__fadd_rn(__fmul_rn(qx, c.x), __fmul_rn(qy, c.y)),
                                        __fmul_rn(qz, c.z));
            // d2 = (q2 + cc) - 2*dot
            const float d2 = __fsub_rn(__fadd_rn(q2, c.w), __fmul_rn(2.0f, dot));
            const int f = base + j;
            if (d2 < best || (d2 == best && f < bestf)) { best = d2; bestf = f; }
        }
    }

    s_best[tid]  = best;
    s_bestf[tid] = bestf;
    __syncthreads();
    if (part == 0) {
        for (int k = 1; k < 4; ++k) {
            const float ob = s_best[tid + 64 * k];
            const int   of = s_bestf[tid + 64 * k];
            if (ob < best || (ob == best && of < bestf)) { best = ob; bestf = of; }
        }
        out[p] = (float)bestf;   // fidx as float (exact for idx < 2^24)
    }
}

// ---------------------------------------------------------------------------
// Kernel 2: per-point correspondence solve (4 outer x 50 Adam steps).
// One thread per point, 256 blocks x 64 threads (1 wave/CU). Reads fidx back
// from d_out. Analytic gradient of
//   L = mean((cV + cN*d - q*S)^2),  cV = interp(V,w)*S, cN = normalize(interp(N,w))*S
// wrt delta=(du,dv,d):
//   g_u = GS*( S*(r.E0) + d*S*((r.F0) - (nh.r)(nh.F0))/|n| )   (E=V edges, F=N edges)
//   g_d = GS*  S*(nh.r),   GS = 2/(3*16384)
// ---------------------------------------------------------------------------
__global__ __launch_bounds__(64)
void solve_kernel(const float* __restrict__ verts,
                  const float* __restrict__ mesh_V,
                  const float* __restrict__ mesh_N,
                  const int*   __restrict__ mesh_F,
                  float*       __restrict__ out)
{
    const int p = blockIdx.x * 64 + threadIdx.x;
    const int f = (int)out[p];

    const float qx = verts[p * 3 + 0];
    const float qy = verts[p * 3 + 1];
    const float qz = verts[p * 3 + 2];

    const int i0 = mesh_F[f * 3 + 0];
    const int i1 = mesh_F[f * 3 + 1];
    const int i2 = mesh_F[f * 3 + 2];

    const float V0x = mesh_V[i0*3+0], V0y = mesh_V[i0*3+1], V0z = mesh_V[i0*3+2];
    const float V1x = mesh_V[i1*3+0], V1y = mesh_V[i1*3+1], V1z = mesh_V[i1*3+2];
    const float V2x = mesh_V[i2*3+0], V2y = mesh_V[i2*3+1], V2z = mesh_V[i2*3+2];
    const float N0x = mesh_N[i0*3+0], N0y = mesh_N[i0*3+1], N0z = mesh_N[i0*3+2];
    const float N1x = mesh_N[i1*3+0], N1y = mesh_N[i1*3+1], N1z = mesh_N[i1*3+2];
    const float N2x = mesh_N[i2*3+0], N2y = mesh_N[i2*3+1], N2z = mesh_N[i2*3+2];

    // edge vectors for gradient dots
    const float E0x = V0x - V2x, E0y = V0y - V2y, E0z = V0z - V2z;
    const float E1x = V1x - V2x, E1y = V1y - V2y, E1z = V1z - V2z;
    const float F0x = N0x - N2x, F0y = N0y - N2y, F0z = N0z - N2z;
    const float F1x = N1x - N2x, F1y = N1y - N2y, F1z = N1z - N2z;

    const float tx = qx * SCALE, ty = qy * SCALE, tz = qz * SCALE;
    const float GS = 2.0f / (3.0f * 16384.0f);
    // exact fp32 constants as jax computes them (Sterbenz-exact subtractions)
    const float B1 = 0.9f,  ONE_M_B1 = 1.0f - 0.9f;
    const float B2 = 0.999f, ONE_M_B2 = 1.0f - 0.999f;

    float vwu = 1.0f / 3.0f, vwv = 1.0f / 3.0f;

    for (int outer = 0; outer < kOuter; ++outer) {
        // d0 = |interp(V, vw) - q| at current vw
        {
            // fallthrough into loop below with du=dv=0
        }
        const float bw0 = (1.0f - vwu) - vwv;
        const float px = ((vwu * V0x + vwv * V1x) + bw0 * V2x);
        const float py = ((vwu * V0y + vwv * V1y) + bw0 * V2y);
        const float pz = ((vwu * V0z + vwv * V1z) + bw0 * V2z);
        const float dx = px - qx, dy = py - qy, dz = pz - qz;
        const float d0 = sqrtf((dx * dx + dy * dy) + dz * dz);

        float du = 0.0f, dv = 0.0f, dd = d0;
        float mAu = 0.0f, mAv = 0.0f, mAd = 0.0f;
        float vAu = 0.0f, vAv = 0.0f, vAd = 0.0f;
        float b1t = 1.0f, b2t = 1.0f;

        for (int it = 0; it < kInner; ++it) {
            const float bu = vwu + du;
            const float bv = vwv + dv;
            const float bw = (1.0f - bu) - bv;

            const float cVx = ((bu * V0x + bv * V1x) + bw * V2x) * SCALE;
            const float cVy = ((bu * V0y + bv * V1y) + bw * V2y) * SCALE;
            const float cVz = ((bu * V0z + bv * V1z) + bw * V2z) * SCALE;

            const float nrx = (bu * N0x + bv * N1x) + bw * N2x;
            const float nry = (bu * N0y + bv * N1y) + bw * N2y;
            const float nrz = (bu * N0z + bv * N1z) + bw * N2z;
            const float nn  = (nrx * nrx + nry * nry) + nrz * nrz;
            const float ln  = sqrtf(nn);
            const float lm  = fmaxf(ln, 1e-12f);
            const float inv = 1.0f / lm;
            const float nhx = nrx * inv, nhy = nry * inv, nhz = nrz * inv;
            const float cNx = nhx * SCALE, cNy = nhy * SCALE, cNz = nhz * SCALE;

            const float rx = (cVx + cNx * dd) - tx;
            const float ry = (cVy + cNy * dd) - ty;
            const float rz = (cVz + cNz * dd) - tz;

            const float rv0  = (rx * E0x + ry * E0y) + rz * E0z;
            const float rv1  = (rx * E1x + ry * E1y) + rz * E1z;
            const float rn0  = (rx * F0x + ry * F0y) + rz * F0z;
            const float rn1  = (rx * F1x + ry * F1y) + rz * F1z;
            const float nf0  = (nhx * F0x + nhy * F0y) + nhz * F0z;
            const float nf1  = (nhx * F1x + nhy * F1y) + nhz * F1z;
            const float nr_r = (nhx * rx + nhy * ry) + nhz * rz;

            const float gu = GS * (SCALE * rv0 + (dd * SCALE) * ((rn0 - nr_r * nf0) * inv));
            const float gv = GS * (SCALE * rv1 + (dd * SCALE) * ((rn1 - nr_r * nf1) * inv));
            const float gd = GS * (SCALE * nr_r);

            mAu = B1 * mAu + ONE_M_B1 * gu;
            mAv = B1 * mAv + ONE_M_B1 * gv;
            mAd = B1 * mAd + ONE_M_B1 * gd;
            vAu = B2 * vAu + ONE_M_B2 * (gu * gu);
            vAv = B2 * vAv + ONE_M_B2 * (gv * gv);
            vAd = B2 * vAd + ONE_M_B2 * (gd * gd);
            b1t *= B1;
            b2t *= B2;
            const float bc1 = 1.0f - b1t;
            const float bc2 = 1.0f - b2t;
            du -= 0.01f * (mAu / bc1) / (sqrtf(vAu / bc2) + 1e-8f);
            dv -= 0.01f * (mAv / bc1) / (sqrtf(vAv / bc2) + 1e-8f);
            dd -= 0.01f * (mAd / bc1) / (sqrtf(vAd / bc2) + 1e-8f);
        }
        vwu += du;
        vwv += dv;
    }

    out[kPts + 2 * p + 0] = vwu;
    out[kPts + 2 * p + 1] = vwv;
    out[3 * kPts + p]     = 0.0f;   // outlier_mask = False
}

extern "C" void kernel_launch(void* const* d_in, const int* in_sizes, int n_in,
                              void* d_out, int out_size, void* d_ws, size_t ws_size,
                              hipStream_t stream) {
    const float* verts  = (const float*)d_in[0];
    const float* mesh_V = (const float*)d_in[1];
    const float* mesh_N = (const float*)d_in[2];
    const int*   mesh_F = (const int*)d_in[3];
    float* out = (float*)d_out;

    hipLaunchKernelGGL(knn_kernel,   dim3(kPts / 64), dim3(256), 0, stream,
                       verts, mesh_V, mesh_F, out);
    hipLaunchKernelGGL(solve_kernel, dim3(kPts / 64), dim3(64), 0, stream,
                       verts, mesh_V, mesh_N, mesh_F, out);
}

// Round 2
// 170.883 us; speedup vs baseline: 2.7132x; 2.7132x over previous
//
#include <hip/hip_runtime.h>
#include <math.h>

// Problem constants (match reference)
constexpr int kVerts = 5000;
constexpr int kFaces = 10000;
constexpr int kPts   = 16384;   // BATCH * N_PTS = 2 * 8192
constexpr int kOuter = 4;
constexpr int kInner = 50;

#define SCALE 10.0f

// ---------------------------------------------------------------------------
// Kernel 1: KNN (K=1) of query points against triangle centers.
//
// grid 256 x block 1024 (16 waves/CU -> ~50% occupancy; was 4 waves -> 12%).
// Each block owns 64 points (lane = tid&63); the 16 wave-partitions
// (part = tid>>6) each scan 1/16 of every 1024-face tile staged in LDS.
// Centers are recomputed during staging (inputs are tiny and L2-resident;
// avoids relying on ws_size). Tile reads are wave-uniform -> LDS broadcast,
// no bank conflicts.
//
// Distance arithmetic is bit-identical to the round-1 passing kernel
// (explicit *_rn ops, same association) so argmin results cannot change.
// First-occurrence tie-break: within one accumulator faces are visited in
// increasing order and strict `<` keeps the first; across accumulators /
// partitions we merge lexicographically by (d2, face_index).
// ---------------------------------------------------------------------------
#define KNN_TILE 1024
#define KNN_PARTS 16
#define KNN_PER_PART (KNN_TILE / KNN_PARTS)   // 64 faces per partition

__global__ __launch_bounds__(1024)
void knn_kernel(const float* __restrict__ verts,
                const float* __restrict__ mesh_V,
                const int*   __restrict__ mesh_F,
                float*       __restrict__ out)
{
    __shared__ float4 s_cent[KNN_TILE];
    __shared__ float  s_best[1024];
    __shared__ int    s_bestf[1024];

    const int tid  = threadIdx.x;
    const int lane = tid & 63;
    const int part = tid >> 6;              // 0..15
    const int p    = blockIdx.x * 64 + lane;

    const float qx = verts[p * 3 + 0];
    const float qy = verts[p * 3 + 1];
    const float qz = verts[p * 3 + 2];
    // (verts**2).sum(-1): (x^2 + y^2) + z^2, plain ops
    const float q2 = __fadd_rn(__fadd_rn(__fmul_rn(qx, qx), __fmul_rn(qy, qy)),
                               __fmul_rn(qz, qz));

    // 4 independent accumulators to break the compare dependency chain
    float bd0 = INFINITY, bd1 = INFINITY, bd2 = INFINITY, bd3 = INFINITY;
    int   bf0 = 0x7fffffff, bf1 = 0x7fffffff, bf2 = 0x7fffffff, bf3 = 0x7fffffff;

    for (int base = 0; base < kFaces; base += KNN_TILE) {
        const int cnt = min(KNN_TILE, kFaces - base);
        __syncthreads();   // protect previous tile's readers
        if (tid < cnt) {
            const int f  = base + tid;
            const int i0 = mesh_F[f * 3 + 0];
            const int i1 = mesh_F[f * 3 + 1];
            const int i2 = mesh_F[f * 3 + 2];
            // mean over the 3 vertices: ((V0+V1)+V2)/3, true division
            const float cx = __fdiv_rn(__fadd_rn(__fadd_rn(mesh_V[i0*3+0], mesh_V[i1*3+0]), mesh_V[i2*3+0]), 3.0f);
            const float cy = __fdiv_rn(__fadd_rn(__fadd_rn(mesh_V[i0*3+1], mesh_V[i1*3+1]), mesh_V[i2*3+1]), 3.0f);
            const float cz = __fdiv_rn(__fadd_rn(__fadd_rn(mesh_V[i0*3+2], mesh_V[i1*3+2]), mesh_V[i2*3+2]), 3.0f);
            const float cc = __fadd_rn(__fadd_rn(__fmul_rn(cx, cx), __fmul_rn(cy, cy)),
                                       __fmul_rn(cz, cz));
            s_cent[tid] = make_float4(cx, cy, cz, cc);
        }
        __syncthreads();

        const int jbeg = part * KNN_PER_PART;
        const int jend = min(jbeg + KNN_PER_PART, cnt);

#define KNN_EVAL(JJ, BD, BF)                                                          \
        {                                                                             \
            const float4 c = s_cent[(JJ)];                                            \
            const float dot = __fadd_rn(__fadd_rn(__fmul_rn(qx, c.x),                 \
                                                  __fmul_rn(qy, c.y)),                \
                                        __fmul_rn(qz, c.z));                          \
            const float d2 = __fsub_rn(__fadd_rn(q2, c.w), __fmul_rn(2.0f, dot));     \
            if (d2 < (BD)) { (BD) = d2; (BF) = base + (JJ); }                         \
        }

        int j = jbeg;
        for (; j + 4 <= jend; j += 4) {
            KNN_EVAL(j + 0, bd0, bf0);
            KNN_EVAL(j + 1, bd1, bf1);
            KNN_EVAL(j + 2, bd2, bf2);
            KNN_EVAL(j + 3, bd3, bf3);
        }
        for (; j < jend; ++j) {
            KNN_EVAL(j, bd0, bf0);   // tail faces are larger than all prior bf0 faces
        }
#undef KNN_EVAL
    }

    // lexicographic merge of the 4 accumulators (smaller f wins ties)
    if (bd1 < bd0 || (bd1 == bd0 && bf1 < bf0)) { bd0 = bd1; bf0 = bf1; }
    if (bd3 < bd2 || (bd3 == bd2 && bf3 < bf2)) { bd2 = bd3; bf2 = bf3; }
    if (bd2 < bd0 || (bd2 == bd0 && bf2 < bf0)) { bd0 = bd2; bf0 = bf2; }

    s_best[tid]  = bd0;
    s_bestf[tid] = bf0;
    __syncthreads();
    if (part == 0) {
        float best  = bd0;
        int   bestf = bf0;
        for (int k = 1; k < KNN_PARTS; ++k) {
            const float ob = s_best[tid + 64 * k];
            const int   of = s_bestf[tid + 64 * k];
            if (ob < best || (ob == best && of < bestf)) { best = ob; bestf = of; }
        }
        out[p] = (float)bestf;   // fidx as float (exact for idx < 2^24)
    }
}

// ---------------------------------------------------------------------------
// Kernel 2: per-point correspondence solve (4 outer x 50 Adam steps).
// One thread per point, 256 blocks x 64 threads. Latency-bound dependent
// chain -> replace all full-precision fp32 div/sqrt sequences (~40 cyc each,
// 10 divides + 4 sqrts per iteration) with v_rcp/v_rsq/v_sqrt approx
// intrinsics (1-ulp). Adam is contractive; path perturbations decay.
// ---------------------------------------------------------------------------
__global__ __launch_bounds__(64)
void solve_kernel(const float* __restrict__ verts,
                  const float* __restrict__ mesh_V,
                  const float* __restrict__ mesh_N,
                  const int*   __restrict__ mesh_F,
                  float*       __restrict__ out)
{
    const int p = blockIdx.x * 64 + threadIdx.x;
    const int f = (int)out[p];

    const float qx = verts[p * 3 + 0];
    const float qy = verts[p * 3 + 1];
    const float qz = verts[p * 3 + 2];

    const int i0 = mesh_F[f * 3 + 0];
    const int i1 = mesh_F[f * 3 + 1];
    const int i2 = mesh_F[f * 3 + 2];

    const float V0x = mesh_V[i0*3+0], V0y = mesh_V[i0*3+1], V0z = mesh_V[i0*3+2];
    const float V1x = mesh_V[i1*3+0], V1y = mesh_V[i1*3+1], V1z = mesh_V[i1*3+2];
    const float V2x = mesh_V[i2*3+0], V2y = mesh_V[i2*3+1], V2z = mesh_V[i2*3+2];
    const float N0x = mesh_N[i0*3+0], N0y = mesh_N[i0*3+1], N0z = mesh_N[i0*3+2];
    const float N1x = mesh_N[i1*3+0], N1y = mesh_N[i1*3+1], N1z = mesh_N[i1*3+2];
    const float N2x = mesh_N[i2*3+0], N2y = mesh_N[i2*3+1], N2z = mesh_N[i2*3+2];

    // edge vectors for gradient dots
    const float E0x = V0x - V2x, E0y = V0y - V2y, E0z = V0z - V2z;
    const float E1x = V1x - V2x, E1y = V1y - V2y, E1z = V1z - V2z;
    const float F0x = N0x - N2x, F0y = N0y - N2y, F0z = N0z - N2z;
    const float F1x = N1x - N2x, F1y = N1y - N2y, F1z = N1z - N2z;

    const float tx = qx * SCALE, ty = qy * SCALE, tz = qz * SCALE;
    const float GS = 2.0f / (3.0f * 16384.0f);
    const float B1 = 0.9f,  ONE_M_B1 = 1.0f - 0.9f;
    const float B2 = 0.999f, ONE_M_B2 = 1.0f - 0.999f;

    float vwu = 1.0f / 3.0f, vwv = 1.0f / 3.0f;

    for (int outer = 0; outer < kOuter; ++outer) {
        const float bw0 = (1.0f - vwu) - vwv;
        const float px = ((vwu * V0x + vwv * V1x) + bw0 * V2x);
        const float py = ((vwu * V0y + vwv * V1y) + bw0 * V2y);
        const float pz = ((vwu * V0z + vwv * V1z) + bw0 * V2z);
        const float dx = px - qx, dy = py - qy, dz = pz - qz;
        const float d0 = __builtin_amdgcn_sqrtf((dx * dx + dy * dy) + dz * dz);

        float du = 0.0f, dv = 0.0f, dd = d0;
        float mAu = 0.0f, mAv = 0.0f, mAd = 0.0f;
        float vAu = 0.0f, vAv = 0.0f, vAd = 0.0f;
        float b1t = 1.0f, b2t = 1.0f;

        for (int it = 0; it < kInner; ++it) {
            const float bu = vwu + du;
            const float bv = vwv + dv;
            const float bw = (1.0f - bu) - bv;

            const float cVx = ((bu * V0x + bv * V1x) + bw * V2x) * SCALE;
            const float cVy = ((bu * V0y + bv * V1y) + bw * V2y) * SCALE;
            const float cVz = ((bu * V0z + bv * V1z) + bw * V2z) * SCALE;

            const float nrx = (bu * N0x + bv * N1x) + bw * N2x;
            const float nry = (bu * N0y + bv * N1y) + bw * N2y;
            const float nrz = (bu * N0z + bv * N1z) + bw * N2z;
            const float nn  = (nrx * nrx + nry * nry) + nrz * nrz;
            // 1/max(sqrt(nn),1e-12) == rsq(nn) for the magnitudes here
            const float inv = __builtin_amdgcn_rsqf(nn);
            const float nhx = nrx * inv, nhy = nry * inv, nhz = nrz * inv;
            const float cNx = nhx * SCALE, cNy = nhy * SCALE, cNz = nhz * SCALE;

            const float rx = (cVx + cNx * dd) - tx;
            const float ry = (cVy + cNy * dd) - ty;
            const float rz = (cVz + cNz * dd) - tz;

            const float rv0  = (rx * E0x + ry * E0y) + rz * E0z;
            const float rv1  = (rx * E1x + ry * E1y) + rz * E1z;
            const float rn0  = (rx * F0x + ry * F0y) + rz * F0z;
            const float rn1  = (rx * F1x + ry * F1y) + rz * F1z;
            const float nf0  = (nhx * F0x + nhy * F0y) + nhz * F0z;
            const float nf1  = (nhx * F1x + nhy * F1y) + nhz * F1z;
            const float nr_r = (nhx * rx + nhy * ry) + nhz * rz;

            const float gu = GS * (SCALE * rv0 + (dd * SCALE) * ((rn0 - nr_r * nf0) * inv));
            const float gv = GS * (SCALE * rv1 + (dd * SCALE) * ((rn1 - nr_r * nf1) * inv));
            const float gd = GS * (SCALE * nr_r);

            mAu = B1 * mAu + ONE_M_B1 * gu;
            mAv = B1 * mAv + ONE_M_B1 * gv;
            mAd = B1 * mAd + ONE_M_B1 * gd;
            vAu = B2 * vAu + ONE_M_B2 * (gu * gu);
            vAv = B2 * vAv + ONE_M_B2 * (gv * gv);
            vAd = B2 * vAd + ONE_M_B2 * (gd * gd);
            b1t *= B1;
            b2t *= B2;
            const float rb1 = __builtin_amdgcn_rcpf(1.0f - b1t);
            const float rb2 = __builtin_amdgcn_rcpf(1.0f - b2t);
            const float den_u = __builtin_amdgcn_sqrtf(vAu * rb2) + 1e-8f;
            const float den_v = __builtin_amdgcn_sqrtf(vAv * rb2) + 1e-8f;
            const float den_d = __builtin_amdgcn_sqrtf(vAd * rb2) + 1e-8f;
            du -= 0.01f * (mAu * rb1) * __builtin_amdgcn_rcpf(den_u);
            dv -= 0.01f * (mAv * rb1) * __builtin_amdgcn_rcpf(den_v);
            dd -= 0.01f * (mAd * rb1) * __builtin_amdgcn_rcpf(den_d);
        }
        vwu += du;
        vwv += dv;
    }

    out[kPts + 2 * p + 0] = vwu;
    out[kPts + 2 * p + 1] = vwv;
    out[3 * kPts + p]     = 0.0f;   // outlier_mask = False
}

extern "C" void kernel_launch(void* const* d_in, const int* in_sizes, int n_in,
                              void* d_out, int out_size, void* d_ws, size_t ws_size,
                              hipStream_t stream) {
    const float* verts  = (const float*)d_in[0];
    const float* mesh_V = (const float*)d_in[1];
    const float* mesh_N = (const float*)d_in[2];
    const int*   mesh_F = (const int*)d_in[3];
    float* out = (float*)d_out;

    hipLaunchKernelGGL(knn_kernel,   dim3(kPts / 64), dim3(1024), 0, stream,
                       verts, mesh_V, mesh_F, out);
    hipLaunchKernelGGL(solve_kernel, dim3(kPts / 64), dim3(64), 0, stream,
                       verts, mesh_V, mesh_N, mesh_F, out);
}

// Round 3
// 154.895 us; speedup vs baseline: 2.9932x; 1.1032x over previous
//
#include <hip/hip_runtime.h>
#include <math.h>

// Problem constants (match reference)
constexpr int kVerts = 5000;
constexpr int kFaces = 10000;
constexpr int kHalf  = kFaces / 2;
constexpr int kPts   = 16384;   // BATCH * N_PTS = 2 * 8192
constexpr int kOuter = 4;
constexpr int kInner = 50;

#define SCALE 10.0f

// ---------------------------------------------------------------------------
// Compile-time Adam bias-correction tables: rb1[t]=1/(1-0.9^(t+1)),
// rb2[t]=1/(1-0.999^(t+1)). Point-independent -> hoisted out of the
// latency-bound per-thread chain entirely (uniform s_load / literals).
// ---------------------------------------------------------------------------
struct BiasTab { float rb1[kInner]; float rb2[kInner]; };
constexpr BiasTab make_tab() {
    BiasTab t{};
    float b1 = 1.0f, b2 = 1.0f;
    for (int i = 0; i < kInner; ++i) {
        b1 *= 0.9f; b2 *= 0.999f;
        t.rb1[i] = 1.0f / (1.0f - b1);
        t.rb2[i] = 1.0f / (1.0f - b2);
    }
    return t;
}
__device__ constexpr BiasTab kTab = make_tab();

// ---------------------------------------------------------------------------
// Kernel 1: KNN (K=1), face dimension split x2 across blocks for occupancy.
//
// grid 512 x block 1024: block = (point-group pg = blockIdx>>1) x
// (face-half h = blockIdx&1). 2 blocks/CU -> 32 waves/CU (was 16 -> 50% cap).
// Each block owns 64 points (lane = tid&63); 16 wave-partitions scan 1/16 of
// each 1024-face LDS tile of its 5000-face half. Per-point (d2,f) candidates
// go to d_ws; the solve kernel merges the two halves lexicographically
// (half 0 wins ties == global first-occurrence, since its indices are lower).
//
// Distance arithmetic is bit-identical to the round-1/2 passing kernels
// (explicit *_rn ops, same association) so argmin results cannot change:
// cancellation noise in (q2+cc)-2dot is ~5e-7 vs best/2nd gaps ~1e-3, so any
// rounding change would flip faces. Frozen.
// ---------------------------------------------------------------------------
#define KNN_TILE 1024
#define KNN_PARTS 16
#define KNN_PER_PART (KNN_TILE / KNN_PARTS)   // 64 faces per partition

__global__ __launch_bounds__(1024)
void knn_kernel(const float* __restrict__ verts,
                const float* __restrict__ mesh_V,
                const int*   __restrict__ mesh_F,
                float*       __restrict__ ws_d2,   // [2][kPts]
                int*         __restrict__ ws_f)    // [2][kPts]
{
    __shared__ float4 s_cent[KNN_TILE];
    __shared__ float  s_best[1024];
    __shared__ int    s_bestf[1024];

    const int tid  = threadIdx.x;
    const int lane = tid & 63;
    const int part = tid >> 6;              // 0..15
    const int pg   = blockIdx.x >> 1;
    const int half = blockIdx.x & 1;
    const int p    = pg * 64 + lane;
    const int fbeg = half * kHalf;
    const int fend = fbeg + kHalf;

    const float qx = verts[p * 3 + 0];
    const float qy = verts[p * 3 + 1];
    const float qz = verts[p * 3 + 2];
    // (verts**2).sum(-1): (x^2 + y^2) + z^2, plain ops
    const float q2 = __fadd_rn(__fadd_rn(__fmul_rn(qx, qx), __fmul_rn(qy, qy)),
                               __fmul_rn(qz, qz));

    // 4 independent accumulators to break the compare dependency chain
    float bd0 = INFINITY, bd1 = INFINITY, bd2 = INFINITY, bd3 = INFINITY;
    int   bf0 = 0x7fffffff, bf1 = 0x7fffffff, bf2 = 0x7fffffff, bf3 = 0x7fffffff;

    for (int base = fbeg; base < fend; base += KNN_TILE) {
        const int cnt = min(KNN_TILE, fend - base);
        __syncthreads();   // protect previous tile's readers
        if (tid < cnt) {
            const int f  = base + tid;
            const int i0 = mesh_F[f * 3 + 0];
            const int i1 = mesh_F[f * 3 + 1];
            const int i2 = mesh_F[f * 3 + 2];
            // mean over the 3 vertices: ((V0+V1)+V2)/3, true division
            const float cx = __fdiv_rn(__fadd_rn(__fadd_rn(mesh_V[i0*3+0], mesh_V[i1*3+0]), mesh_V[i2*3+0]), 3.0f);
            const float cy = __fdiv_rn(__fadd_rn(__fadd_rn(mesh_V[i0*3+1], mesh_V[i1*3+1]), mesh_V[i2*3+1]), 3.0f);
            const float cz = __fdiv_rn(__fadd_rn(__fadd_rn(mesh_V[i0*3+2], mesh_V[i1*3+2]), mesh_V[i2*3+2]), 3.0f);
            const float cc = __fadd_rn(__fadd_rn(__fmul_rn(cx, cx), __fmul_rn(cy, cy)),
                                       __fmul_rn(cz, cz));
            s_cent[tid] = make_float4(cx, cy, cz, cc);
        }
        __syncthreads();

        const int jbeg = part * KNN_PER_PART;
        const int jend = min(jbeg + KNN_PER_PART, cnt);

#define KNN_EVAL(JJ, BD, BF)                                                          \
        {                                                                             \
            const float4 c = s_cent[(JJ)];                                            \
            const float dot = __fadd_rn(__fadd_rn(__fmul_rn(qx, c.x),                 \
                                                  __fmul_rn(qy, c.y)),                \
                                        __fmul_rn(qz, c.z));                          \
            const float d2 = __fsub_rn(__fadd_rn(q2, c.w), __fmul_rn(2.0f, dot));     \
            if (d2 < (BD)) { (BD) = d2; (BF) = base + (JJ); }                         \
        }

        int j = jbeg;
        for (; j + 4 <= jend; j += 4) {
            KNN_EVAL(j + 0, bd0, bf0);
            KNN_EVAL(j + 1, bd1, bf1);
            KNN_EVAL(j + 2, bd2, bf2);
            KNN_EVAL(j + 3, bd3, bf3);
        }
        for (; j < jend; ++j) {
            KNN_EVAL(j, bd0, bf0);   // tail faces are larger than all prior bf0 faces
        }
#undef KNN_EVAL
    }

    // lexicographic merge of the 4 accumulators (smaller f wins ties)
    if (bd1 < bd0 || (bd1 == bd0 && bf1 < bf0)) { bd0 = bd1; bf0 = bf1; }
    if (bd3 < bd2 || (bd3 == bd2 && bf3 < bf2)) { bd2 = bd3; bf2 = bf3; }
    if (bd2 < bd0 || (bd2 == bd0 && bf2 < bf0)) { bd0 = bd2; bf0 = bf2; }

    s_best[tid]  = bd0;
    s_bestf[tid] = bf0;
    __syncthreads();
    if (part == 0) {
        float best  = bd0;
        int   bestf = bf0;
        for (int k = 1; k < KNN_PARTS; ++k) {
            const float ob = s_best[tid + 64 * k];
            const int   of = s_bestf[tid + 64 * k];
            if (ob < best || (ob == best && of < bestf)) { best = ob; bestf = of; }
        }
        ws_d2[half * kPts + p] = best;
        ws_f [half * kPts + p] = bestf;
    }
}

// ---------------------------------------------------------------------------
// Kernel 2: merge the two face-half candidates, then per-point solve
// (4 outer x 50 Adam steps). One thread per point, 256 blocks x 64 threads.
// Pure latency-bound dependent chain (256 waves total = 1 wave/CU, nothing
// to co-schedule) -> shorten the chain:
//   * bias corrections from compile-time tables (removes 2 rcp + muls/iter)
//   * mhat/(sqrt(vhat)+1e-8)  ->  mhat*rsq(vhat+1e-16)   (<=5e-5 rel diff at
//     observed vhat ~1e-7; Adam is contractive, drift decays)
//   * partial unroll so u/v/d streams interleave across iterations
// ---------------------------------------------------------------------------
__global__ __launch_bounds__(64)
void solve_kernel(const float* __restrict__ verts,
                  const float* __restrict__ mesh_V,
                  const float* __restrict__ mesh_N,
                  const int*   __restrict__ mesh_F,
                  const float* __restrict__ ws_d2,
                  const int*   __restrict__ ws_f,
                  float*       __restrict__ out)
{
    const int p = blockIdx.x * 64 + threadIdx.x;

    // merge halves: half 0 wins ties (lower indices) == first occurrence
    const float da = ws_d2[p];
    const float db = ws_d2[kPts + p];
    const int   fa = ws_f[p];
    const int   fb = ws_f[kPts + p];
    const int   f  = (db < da) ? fb : fa;
    out[p] = (float)f;   // fidx as float (exact for idx < 2^24)

    const float qx = verts[p * 3 + 0];
    const float qy = verts[p * 3 + 1];
    const float qz = verts[p * 3 + 2];

    const int i0 = mesh_F[f * 3 + 0];
    const int i1 = mesh_F[f * 3 + 1];
    const int i2 = mesh_F[f * 3 + 2];

    const float V0x = mesh_V[i0*3+0], V0y = mesh_V[i0*3+1], V0z = mesh_V[i0*3+2];
    const float V1x = mesh_V[i1*3+0], V1y = mesh_V[i1*3+1], V1z = mesh_V[i1*3+2];
    const float V2x = mesh_V[i2*3+0], V2y = mesh_V[i2*3+1], V2z = mesh_V[i2*3+2];
    const float N0x = mesh_N[i0*3+0], N0y = mesh_N[i0*3+1], N0z = mesh_N[i0*3+2];
    const float N1x = mesh_N[i1*3+0], N1y = mesh_N[i1*3+1], N1z = mesh_N[i1*3+2];
    const float N2x = mesh_N[i2*3+0], N2y = mesh_N[i2*3+1], N2z = mesh_N[i2*3+2];

    // edge vectors for gradient dots
    const float E0x = V0x - V2x, E0y = V0y - V2y, E0z = V0z - V2z;
    const float E1x = V1x - V2x, E1y = V1y - V2y, E1z = V1z - V2z;
    const float F0x = N0x - N2x, F0y = N0y - N2y, F0z = N0z - N2z;
    const float F1x = N1x - N2x, F1y = N1y - N2y, F1z = N1z - N2z;

    const float tx = qx * SCALE, ty = qy * SCALE, tz = qz * SCALE;
    const float GS = 2.0f / (3.0f * 16384.0f);
    const float B1 = 0.9f,  ONE_M_B1 = 1.0f - 0.9f;
    const float B2 = 0.999f, ONE_M_B2 = 1.0f - 0.999f;

    float vwu = 1.0f / 3.0f, vwv = 1.0f / 3.0f;

    for (int outer = 0; outer < kOuter; ++outer) {
        const float bw0 = (1.0f - vwu) - vwv;
        const float px = ((vwu * V0x + vwv * V1x) + bw0 * V2x);
        const float py = ((vwu * V0y + vwv * V1y) + bw0 * V2y);
        const float pz = ((vwu * V0z + vwv * V1z) + bw0 * V2z);
        const float dx = px - qx, dy = py - qy, dz = pz - qz;
        const float d0 = __builtin_amdgcn_sqrtf((dx * dx + dy * dy) + dz * dz);

        float du = 0.0f, dv = 0.0f, dd = d0;
        float mAu = 0.0f, mAv = 0.0f, mAd = 0.0f;
        float vAu = 0.0f, vAv = 0.0f, vAd = 0.0f;

#pragma unroll 10
        for (int it = 0; it < kInner; ++it) {
            const float bu = vwu + du;
            const float bv = vwv + dv;
            const float bw = (1.0f - bu) - bv;

            const float cVx = ((bu * V0x + bv * V1x) + bw * V2x) * SCALE;
            const float cVy = ((bu * V0y + bv * V1y) + bw * V2y) * SCALE;
            const float cVz = ((bu * V0z + bv * V1z) + bw * V2z) * SCALE;

            const float nrx = (bu * N0x + bv * N1x) + bw * N2x;
            const float nry = (bu * N0y + bv * N1y) + bw * N2y;
            const float nrz = (bu * N0z + bv * N1z) + bw * N2z;
            const float nn  = (nrx * nrx + nry * nry) + nrz * nrz;
            // 1/max(sqrt(nn),1e-12) == rsq(nn) for the magnitudes here
            const float inv = __builtin_amdgcn_rsqf(nn);
            const float nhx = nrx * inv, nhy = nry * inv, nhz = nrz * inv;
            const float cNx = nhx * SCALE, cNy = nhy * SCALE, cNz = nhz * SCALE;

            const float rx = (cVx + cNx * dd) - tx;
            const float ry = (cVy + cNy * dd) - ty;
            const float rz = (cVz + cNz * dd) - tz;

            const float rv0  = (rx * E0x + ry * E0y) + rz * E0z;
            const float rv1  = (rx * E1x + ry * E1y) + rz * E1z;
            const float rn0  = (rx * F0x + ry * F0y) + rz * F0z;
            const float rn1  = (rx * F1x + ry * F1y) + rz * F1z;
            const float nf0  = (nhx * F0x + nhy * F0y) + nhz * F0z;
            const float nf1  = (nhx * F1x + nhy * F1y) + nhz * F1z;
            const float nr_r = (nhx * rx + nhy * ry) + nhz * rz;

            const float gu = GS * (SCALE * rv0 + (dd * SCALE) * ((rn0 - nr_r * nf0) * inv));
            const float gv = GS * (SCALE * rv1 + (dd * SCALE) * ((rn1 - nr_r * nf1) * inv));
            const float gd = GS * (SCALE * nr_r);

            mAu = B1 * mAu + ONE_M_B1 * gu;
            mAv = B1 * mAv + ONE_M_B1 * gv;
            mAd = B1 * mAd + ONE_M_B1 * gd;
            vAu = B2 * vAu + ONE_M_B2 * (gu * gu);
            vAv = B2 * vAv + ONE_M_B2 * (gv * gv);
            vAd = B2 * vAd + ONE_M_B2 * (gd * gd);

            const float rb1 = kTab.rb1[it];
            const float rb2 = kTab.rb2[it];
            // mhat/(sqrt(vhat)+1e-8) ~= mhat * rsq(vhat + 1e-16)
            const float su = __builtin_amdgcn_rsqf(vAu * rb2 + 1e-16f);
            const float sv = __builtin_amdgcn_rsqf(vAv * rb2 + 1e-16f);
            const float sd = __builtin_amdgcn_rsqf(vAd * rb2 + 1e-16f);
            du -= 0.01f * (mAu * rb1) * su;
            dv -= 0.01f * (mAv * rb1) * sv;
            dd -= 0.01f * (mAd * rb1) * sd;
        }
        vwu += du;
        vwv += dv;
    }

    out[kPts + 2 * p + 0] = vwu;
    out[kPts + 2 * p + 1] = vwv;
    out[3 * kPts + p]     = 0.0f;   // outlier_mask = False
}

extern "C" void kernel_launch(void* const* d_in, const int* in_sizes, int n_in,
                              void* d_out, int out_size, void* d_ws, size_t ws_size,
                              hipStream_t stream) {
    const float* verts  = (const float*)d_in[0];
    const float* mesh_V = (const float*)d_in[1];
    const float* mesh_N = (const float*)d_in[2];
    const int*   mesh_F = (const int*)d_in[3];
    float* out = (float*)d_out;

    float* ws_d2 = (float*)d_ws;                 // [2][kPts] floats
    int*   ws_f  = (int*)((char*)d_ws + 2 * kPts * sizeof(float));  // [2][kPts] ints

    hipLaunchKernelGGL(knn_kernel,   dim3(2 * kPts / 64), dim3(1024), 0, stream,
                       verts, mesh_V, mesh_F, ws_d2, ws_f);
    hipLaunchKernelGGL(solve_kernel, dim3(kPts / 64), dim3(64), 0, stream,
                       verts, mesh_V, mesh_N, mesh_F, ws_d2, ws_f, out);
}

// Round 4
// 140.309 us; speedup vs baseline: 3.3044x; 1.1040x over previous
//
#include <hip/hip_runtime.h>
#include <math.h>

// Problem constants (match reference)
constexpr int kVerts = 5000;
constexpr int kFaces = 10000;
constexpr int kHalf  = kFaces / 2;
constexpr int kPts   = 16384;   // BATCH * N_PTS = 2 * 8192
constexpr int kOuter = 4;
constexpr int kInner = 50;

#define SCALE 10.0f

// ---------------------------------------------------------------------------
// Compile-time Adam bias-correction tables (round-3, unchanged).
// ---------------------------------------------------------------------------
struct BiasTab { float rb1[kInner]; float rb2[kInner]; };
constexpr BiasTab make_tab() {
    BiasTab t{};
    float b1 = 1.0f, b2 = 1.0f;
    for (int i = 0; i < kInner; ++i) {
        b1 *= 0.9f; b2 *= 0.999f;
        t.rb1[i] = 1.0f / (1.0f - b1);
        t.rb2[i] = 1.0f / (1.0f - b2);
    }
    return t;
}
__device__ constexpr BiasTab kTab = make_tab();

// ---------------------------------------------------------------------------
// Kernel 0: precompute triangle centers ONCE (round-3 recomputed them in
// every one of 512 knn blocks, with random-index mesh_V gathers each time).
// Bit-identical *_rn formula -> identical center bits -> identical argmin.
// cent[f] = (cx, cy, cz, cc = |c|^2)
// ---------------------------------------------------------------------------
__global__ __launch_bounds__(256)
void centers_kernel(const float* __restrict__ mesh_V,
                    const int*   __restrict__ mesh_F,
                    float4*      __restrict__ cent)
{
    const int f = blockIdx.x * 256 + threadIdx.x;
    if (f >= kFaces) return;
    const int i0 = mesh_F[f * 3 + 0];
    const int i1 = mesh_F[f * 3 + 1];
    const int i2 = mesh_F[f * 3 + 2];
    const float cx = __fdiv_rn(__fadd_rn(__fadd_rn(mesh_V[i0*3+0], mesh_V[i1*3+0]), mesh_V[i2*3+0]), 3.0f);
    const float cy = __fdiv_rn(__fadd_rn(__fadd_rn(mesh_V[i0*3+1], mesh_V[i1*3+1]), mesh_V[i2*3+1]), 3.0f);
    const float cz = __fdiv_rn(__fadd_rn(__fadd_rn(mesh_V[i0*3+2], mesh_V[i1*3+2]), mesh_V[i2*3+2]), 3.0f);
    const float cc = __fadd_rn(__fadd_rn(__fmul_rn(cx, cx), __fmul_rn(cy, cy)),
                               __fmul_rn(cz, cz));
    cent[f] = make_float4(cx, cy, cz, cc);
}

// ---------------------------------------------------------------------------
// Kernel 1: KNN (K=1). Round-3 was LDS-pipe-bound: ds_read_b128 per
// (thread,face) cost ~24.6k LDS-pipe cyc per CU per tile vs 10.2k VALU.
// Rewrite: NO center staging in LDS. Each of the 16 waves in a block scans a
// contiguous face range of its half with WAVE-UNIFORM center loads
// (readfirstlane-forced uniform index) -> scalar s_load_dwordx4 (or at worst
// one 16B L2 request per wave) -> LDS pipe out of the loop entirely.
// VALU floor ~23 us.
//
// grid 512 x block 1024: block = (point-group) x (face-half). Per-point
// (d2,f) candidates to d_ws; solve merges halves (half 0 wins ties ==
// first occurrence). Distance arithmetic bit-identical to rounds 1-3.
// ---------------------------------------------------------------------------
#define KNN_PARTS 16

__global__ __launch_bounds__(1024)
void knn_kernel(const float* __restrict__ verts,
                const float4* __restrict__ cent,
                float*        __restrict__ ws_d2,   // [2][kPts]
                int*          __restrict__ ws_f)    // [2][kPts]
{
    __shared__ float s_best[1024];
    __shared__ int   s_bestf[1024];

    const int tid  = threadIdx.x;
    const int lane = tid & 63;
    // force wave-uniformity so the compiler can prove scalar-ness
    const int part = __builtin_amdgcn_readfirstlane(tid >> 6);   // 0..15
    const int pg   = blockIdx.x >> 1;
    const int half = blockIdx.x & 1;
    const int p    = pg * 64 + lane;

    const float qx = verts[p * 3 + 0];
    const float qy = verts[p * 3 + 1];
    const float qz = verts[p * 3 + 2];
    // (verts**2).sum(-1): (x^2 + y^2) + z^2, plain ops
    const float q2 = __fadd_rn(__fadd_rn(__fmul_rn(qx, qx), __fmul_rn(qy, qy)),
                               __fmul_rn(qz, qz));

    // this wave's contiguous face range within its half
    const int fbeg = half * kHalf + (part * kHalf) / KNN_PARTS;
    const int fend = half * kHalf + ((part + 1) * kHalf) / KNN_PARTS;

    // 4 independent accumulators to break the compare dependency chain
    float bd0 = INFINITY, bd1 = INFINITY, bd2 = INFINITY, bd3 = INFINITY;
    int   bf0 = 0x7fffffff, bf1 = 0x7fffffff, bf2 = 0x7fffffff, bf3 = 0x7fffffff;

#define KNN_EVAL(FF, C, BD, BF)                                                       \
    {                                                                                 \
        const float dot = __fadd_rn(__fadd_rn(__fmul_rn(qx, (C).x),                   \
                                              __fmul_rn(qy, (C).y)),                  \
                                    __fmul_rn(qz, (C).z));                            \
        const float d2 = __fsub_rn(__fadd_rn(q2, (C).w), __fmul_rn(2.0f, dot));       \
        if (d2 < (BD)) { (BD) = d2; (BF) = (FF); }                                    \
    }

    int f = fbeg;
#pragma unroll 2
    for (; f + 4 <= fend; f += 4) {
        const float4 c0 = cent[f + 0];   // uniform address -> scalar load
        const float4 c1 = cent[f + 1];
        const float4 c2 = cent[f + 2];
        const float4 c3 = cent[f + 3];
        KNN_EVAL(f + 0, c0, bd0, bf0);
        KNN_EVAL(f + 1, c1, bd1, bf1);
        KNN_EVAL(f + 2, c2, bd2, bf2);
        KNN_EVAL(f + 3, c3, bd3, bf3);
    }
    for (; f < fend; ++f) {
        const float4 c0 = cent[f];
        KNN_EVAL(f, c0, bd0, bf0);   // tail faces exceed all prior bf0 faces
    }
#undef KNN_EVAL

    // lexicographic merge of the 4 accumulators (smaller f wins ties)
    if (bd1 < bd0 || (bd1 == bd0 && bf1 < bf0)) { bd0 = bd1; bf0 = bf1; }
    if (bd3 < bd2 || (bd3 == bd2 && bf3 < bf2)) { bd2 = bd3; bf2 = bf3; }
    if (bd2 < bd0 || (bd2 == bd0 && bf2 < bf0)) { bd0 = bd2; bf0 = bf2; }

    s_best[tid]  = bd0;
    s_bestf[tid] = bf0;
    __syncthreads();
    if (part == 0) {
        float best  = bd0;
        int   bestf = bf0;
        for (int k = 1; k < KNN_PARTS; ++k) {
            const float ob = s_best[tid + 64 * k];
            const int   of = s_bestf[tid + 64 * k];
            if (ob < best || (ob == best && of < bestf)) { best = ob; bestf = of; }
        }
        ws_d2[half * kPts + p] = best;
        ws_f [half * kPts + p] = bestf;
    }
}

// ---------------------------------------------------------------------------
// Kernel 2: solve — BYTE-IDENTICAL to round 3 (passed at absmax 0.338).
// One experiment variable per round; solve chain analysis continues next
// round with the knn fix locked in.
// ---------------------------------------------------------------------------
__global__ __launch_bounds__(64)
void solve_kernel(const float* __restrict__ verts,
                  const float* __restrict__ mesh_V,
                  const float* __restrict__ mesh_N,
                  const int*   __restrict__ mesh_F,
                  const float* __restrict__ ws_d2,
                  const int*   __restrict__ ws_f,
                  float*       __restrict__ out)
{
    const int p = blockIdx.x * 64 + threadIdx.x;

    // merge halves: half 0 wins ties (lower indices) == first occurrence
    const float da = ws_d2[p];
    const float db = ws_d2[kPts + p];
    const int   fa = ws_f[p];
    const int   fb = ws_f[kPts + p];
    const int   f  = (db < da) ? fb : fa;
    out[p] = (float)f;   // fidx as float (exact for idx < 2^24)

    const float qx = verts[p * 3 + 0];
    const float qy = verts[p * 3 + 1];
    const float qz = verts[p * 3 + 2];

    const int i0 = mesh_F[f * 3 + 0];
    const int i1 = mesh_F[f * 3 + 1];
    const int i2 = mesh_F[f * 3 + 2];

    const float V0x = mesh_V[i0*3+0], V0y = mesh_V[i0*3+1], V0z = mesh_V[i0*3+2];
    const float V1x = mesh_V[i1*3+0], V1y = mesh_V[i1*3+1], V1z = mesh_V[i1*3+2];
    const float V2x = mesh_V[i2*3+0], V2y = mesh_V[i2*3+1], V2z = mesh_V[i2*3+2];
    const float N0x = mesh_N[i0*3+0], N0y = mesh_N[i0*3+1], N0z = mesh_N[i0*3+2];
    const float N1x = mesh_N[i1*3+0], N1y = mesh_N[i1*3+1], N1z = mesh_N[i1*3+2];
    const float N2x = mesh_N[i2*3+0], N2y = mesh_N[i2*3+1], N2z = mesh_N[i2*3+2];

    // edge vectors for gradient dots
    const float E0x = V0x - V2x, E0y = V0y - V2y, E0z = V0z - V2z;
    const float E1x = V1x - V2x, E1y = V1y - V2y, E1z = V1z - V2z;
    const float F0x = N0x - N2x, F0y = N0y - N2y, F0z = N0z - N2z;
    const float F1x = N1x - N2x, F1y = N1y - N2y, F1z = N1z - N2z;

    const float tx = qx * SCALE, ty = qy * SCALE, tz = qz * SCALE;
    const float GS = 2.0f / (3.0f * 16384.0f);
    const float B1 = 0.9f,  ONE_M_B1 = 1.0f - 0.9f;
    const float B2 = 0.999f, ONE_M_B2 = 1.0f - 0.999f;

    float vwu = 1.0f / 3.0f, vwv = 1.0f / 3.0f;

    for (int outer = 0; outer < kOuter; ++outer) {
        const float bw0 = (1.0f - vwu) - vwv;
        const float px = ((vwu * V0x + vwv * V1x) + bw0 * V2x);
        const float py = ((vwu * V0y + vwv * V1y) + bw0 * V2y);
        const float pz = ((vwu * V0z + vwv * V1z) + bw0 * V2z);
        const float dx = px - qx, dy = py - qy, dz = pz - qz;
        const float d0 = __builtin_amdgcn_sqrtf((dx * dx + dy * dy) + dz * dz);

        float du = 0.0f, dv = 0.0f, dd = d0;
        float mAu = 0.0f, mAv = 0.0f, mAd = 0.0f;
        float vAu = 0.0f, vAv = 0.0f, vAd = 0.0f;

#pragma unroll 10
        for (int it = 0; it < kInner; ++it) {
            const float bu = vwu + du;
            const float bv = vwv + dv;
            const float bw = (1.0f - bu) - bv;

            const float cVx = ((bu * V0x + bv * V1x) + bw * V2x) * SCALE;
            const float cVy = ((bu * V0y + bv * V1y) + bw * V2y) * SCALE;
            const float cVz = ((bu * V0z + bv * V1z) + bw * V2z) * SCALE;

            const float nrx = (bu * N0x + bv * N1x) + bw * N2x;
            const float nry = (bu * N0y + bv * N1y) + bw * N2y;
            const float nrz = (bu * N0z + bv * N1z) + bw * N2z;
            const float nn  = (nrx * nrx + nry * nry) + nrz * nrz;
            // 1/max(sqrt(nn),1e-12) == rsq(nn) for the magnitudes here
            const float inv = __builtin_amdgcn_rsqf(nn);
            const float nhx = nrx * inv, nhy = nry * inv, nhz = nrz * inv;
            const float cNx = nhx * SCALE, cNy = nhy * SCALE, cNz = nhz * SCALE;

            const float rx = (cVx + cNx * dd) - tx;
            const float ry = (cVy + cNy * dd) - ty;
            const float rz = (cVz + cNz * dd) - tz;

            const float rv0  = (rx * E0x + ry * E0y) + rz * E0z;
            const float rv1  = (rx * E1x + ry * E1y) + rz * E1z;
            const float rn0  = (rx * F0x + ry * F0y) + rz * F0z;
            const float rn1  = (rx * F1x + ry * F1y) + rz * F1z;
            const float nf0  = (nhx * F0x + nhy * F0y) + nhz * F0z;
            const float nf1  = (nhx * F1x + nhy * F1y) + nhz * F1z;
            const float nr_r = (nhx * rx + nhy * ry) + nhz * rz;

            const float gu = GS * (SCALE * rv0 + (dd * SCALE) * ((rn0 - nr_r * nf0) * inv));
            const float gv = GS * (SCALE * rv1 + (dd * SCALE) * ((rn1 - nr_r * nf1) * inv));
            const float gd = GS * (SCALE * nr_r);

            mAu = B1 * mAu + ONE_M_B1 * gu;
            mAv = B1 * mAv + ONE_M_B1 * gv;
            mAd = B1 * mAd + ONE_M_B1 * gd;
            vAu = B2 * vAu + ONE_M_B2 * (gu * gu);
            vAv = B2 * vAv + ONE_M_B2 * (gv * gv);
            vAd = B2 * vAd + ONE_M_B2 * (gd * gd);

            const float rb1 = kTab.rb1[it];
            const float rb2 = kTab.rb2[it];
            // mhat/(sqrt(vhat)+1e-8) ~= mhat * rsq(vhat + 1e-16)
            const float su = __builtin_amdgcn_rsqf(vAu * rb2 + 1e-16f);
            const float sv = __builtin_amdgcn_rsqf(vAv * rb2 + 1e-16f);
            const float sd = __builtin_amdgcn_rsqf(vAd * rb2 + 1e-16f);
            du -= 0.01f * (mAu * rb1) * su;
            dv -= 0.01f * (mAv * rb1) * sv;
            dd -= 0.01f * (mAd * rb1) * sd;
        }
        vwu += du;
        vwv += dv;
    }

    out[kPts + 2 * p + 0] = vwu;
    out[kPts + 2 * p + 1] = vwv;
    out[3 * kPts + p]     = 0.0f;   // outlier_mask = False
}

extern "C" void kernel_launch(void* const* d_in, const int* in_sizes, int n_in,
                              void* d_out, int out_size, void* d_ws, size_t ws_size,
                              hipStream_t stream) {
    const float* verts  = (const float*)d_in[0];
    const float* mesh_V = (const float*)d_in[1];
    const float* mesh_N = (const float*)d_in[2];
    const int*   mesh_F = (const int*)d_in[3];
    float* out = (float*)d_out;

    // workspace layout: centers | d2 candidates | face candidates
    float4* ws_cent = (float4*)d_ws;                                   // kFaces float4
    float*  ws_d2   = (float*)((char*)d_ws + kFaces * sizeof(float4)); // [2][kPts]
    int*    ws_f    = (int*)((char*)ws_d2 + 2 * kPts * sizeof(float)); // [2][kPts]

    hipLaunchKernelGGL(centers_kernel, dim3((kFaces + 255) / 256), dim3(256), 0, stream,
                       mesh_V, mesh_F, ws_cent);
    hipLaunchKernelGGL(knn_kernel,     dim3(2 * kPts / 64), dim3(1024), 0, stream,
                       verts, ws_cent, ws_d2, ws_f);
    hipLaunchKernelGGL(solve_kernel,   dim3(kPts / 64), dim3(64), 0, stream,
                       verts, mesh_V, mesh_N, mesh_F, ws_d2, ws_f, out);
}

// Round 5
// 139.339 us; speedup vs baseline: 3.3274x; 1.0070x over previous
//
#include <hip/hip_runtime.h>
#include <math.h>

// Problem constants (match reference)
constexpr int kVerts = 5000;
constexpr int kFaces = 10000;
constexpr int kHalf  = kFaces / 2;
constexpr int kPts   = 16384;   // BATCH * N_PTS = 2 * 8192
constexpr int kOuter = 4;
constexpr int kInner = 50;

#define SCALE 10.0f

// ---------------------------------------------------------------------------
// Compile-time Adam bias-correction tables. With the inner loop FULLY
// unrolled these fold to inline literals (round-3/4's partial unroll left
// `it` dynamic -> 2 s_load + lgkmcnt(0) per iteration, fully exposed at
// 1 wave/SIMD -- that was the hidden cost).
// ---------------------------------------------------------------------------
struct BiasTab { float rb1[kInner]; float rb2[kInner]; };
constexpr BiasTab make_tab() {
    BiasTab t{};
    float b1 = 1.0f, b2 = 1.0f;
    for (int i = 0; i < kInner; ++i) {
        b1 *= 0.9f; b2 *= 0.999f;
        t.rb1[i] = 1.0f / (1.0f - b1);
        t.rb2[i] = 1.0f / (1.0f - b2);
    }
    return t;
}
constexpr BiasTab kTab = make_tab();

// ---------------------------------------------------------------------------
// Kernel 0: precompute triangle centers once (bit-identical *_rn formula).
// cent[f] = (cx, cy, cz, cc = |c|^2)
// ---------------------------------------------------------------------------
__global__ __launch_bounds__(256)
void centers_kernel(const float* __restrict__ mesh_V,
                    const int*   __restrict__ mesh_F,
                    float4*      __restrict__ cent)
{
    const int f = blockIdx.x * 256 + threadIdx.x;
    if (f >= kFaces) return;
    const int i0 = mesh_F[f * 3 + 0];
    const int i1 = mesh_F[f * 3 + 1];
    const int i2 = mesh_F[f * 3 + 2];
    const float cx = __fdiv_rn(__fadd_rn(__fadd_rn(mesh_V[i0*3+0], mesh_V[i1*3+0]), mesh_V[i2*3+0]), 3.0f);
    const float cy = __fdiv_rn(__fadd_rn(__fadd_rn(mesh_V[i0*3+1], mesh_V[i1*3+1]), mesh_V[i2*3+1]), 3.0f);
    const float cz = __fdiv_rn(__fadd_rn(__fadd_rn(mesh_V[i0*3+2], mesh_V[i1*3+2]), mesh_V[i2*3+2]), 3.0f);
    const float cc = __fadd_rn(__fadd_rn(__fmul_rn(cx, cx), __fmul_rn(cy, cy)),
                               __fmul_rn(cz, cz));
    cent[f] = make_float4(cx, cy, cz, cc);
}

// ---------------------------------------------------------------------------
// Kernel 1: KNN (K=1). Wave-uniform scalar-load scan (round-4 structure).
// Round-4 counters: VALUBusy 49% at occupancy 66% -> stalled on lgkmcnt
// between 8-load batches. Change: unroll 4 -> 16 scalar loads in flight per
// waitcnt batch. Distance arithmetic bit-identical (frozen since round 1).
// ---------------------------------------------------------------------------
#define KNN_PARTS 16

__global__ __launch_bounds__(1024)
void knn_kernel(const float* __restrict__ verts,
                const float4* __restrict__ cent,
                float*        __restrict__ ws_d2,   // [2][kPts]
                int*          __restrict__ ws_f)    // [2][kPts]
{
    __shared__ float s_best[1024];
    __shared__ int   s_bestf[1024];

    const int tid  = threadIdx.x;
    const int lane = tid & 63;
    // force wave-uniformity so the compiler can prove scalar-ness
    const int part = __builtin_amdgcn_readfirstlane(tid >> 6);   // 0..15
    const int pg   = blockIdx.x >> 1;
    const int half = blockIdx.x & 1;
    const int p    = pg * 64 + lane;

    const float qx = verts[p * 3 + 0];
    const float qy = verts[p * 3 + 1];
    const float qz = verts[p * 3 + 2];
    // (verts**2).sum(-1): (x^2 + y^2) + z^2, plain ops
    const float q2 = __fadd_rn(__fadd_rn(__fmul_rn(qx, qx), __fmul_rn(qy, qy)),
                               __fmul_rn(qz, qz));

    // this wave's contiguous face range within its half
    const int fbeg = half * kHalf + (part * kHalf) / KNN_PARTS;
    const int fend = half * kHalf + ((part + 1) * kHalf) / KNN_PARTS;

    // 4 independent accumulators to break the compare dependency chain
    float bd0 = INFINITY, bd1 = INFINITY, bd2 = INFINITY, bd3 = INFINITY;
    int   bf0 = 0x7fffffff, bf1 = 0x7fffffff, bf2 = 0x7fffffff, bf3 = 0x7fffffff;

#define KNN_EVAL(FF, C, BD, BF)                                                       \
    {                                                                                 \
        const float dot = __fadd_rn(__fadd_rn(__fmul_rn(qx, (C).x),                   \
                                              __fmul_rn(qy, (C).y)),                  \
                                    __fmul_rn(qz, (C).z));                            \
        const float d2 = __fsub_rn(__fadd_rn(q2, (C).w), __fmul_rn(2.0f, dot));       \
        if (d2 < (BD)) { (BD) = d2; (BF) = (FF); }                                    \
    }

    int f = fbeg;
#pragma unroll 4
    for (; f + 4 <= fend; f += 4) {
        const float4 c0 = cent[f + 0];   // uniform address -> scalar load
        const float4 c1 = cent[f + 1];
        const float4 c2 = cent[f + 2];
        const float4 c3 = cent[f + 3];
        KNN_EVAL(f + 0, c0, bd0, bf0);
        KNN_EVAL(f + 1, c1, bd1, bf1);
        KNN_EVAL(f + 2, c2, bd2, bf2);
        KNN_EVAL(f + 3, c3, bd3, bf3);
    }
    for (; f < fend; ++f) {
        const float4 c0 = cent[f];
        KNN_EVAL(f, c0, bd0, bf0);   // tail faces exceed all prior bf0 faces
    }
#undef KNN_EVAL

    // lexicographic merge of the 4 accumulators (smaller f wins ties)
    if (bd1 < bd0 || (bd1 == bd0 && bf1 < bf0)) { bd0 = bd1; bf0 = bf1; }
    if (bd3 < bd2 || (bd3 == bd2 && bf3 < bf2)) { bd2 = bd3; bf2 = bf3; }
    if (bd2 < bd0 || (bd2 == bd0 && bf2 < bf0)) { bd0 = bd2; bf0 = bf2; }

    s_best[tid]  = bd0;
    s_bestf[tid] = bf0;
    __syncthreads();
    if (part == 0) {
        float best  = bd0;
        int   bestf = bf0;
        for (int k = 1; k < KNN_PARTS; ++k) {
            const float ob = s_best[tid + 64 * k];
            const int   of = s_bestf[tid + 64 * k];
            if (ob < best || (ob == best && of < bestf)) { best = ob; bestf = of; }
        }
        ws_d2[half * kPts + p] = best;
        ws_f [half * kPts + p] = bestf;
    }
}

// ---------------------------------------------------------------------------
// Kernel 2: solve — SAME MATH as rounds 3/4 (absmax must remain exactly
// 0.3383789). Only change: FULL unroll of the inner 50-step loop, so the
// bias-correction table reads become inline literals instead of per-
// iteration s_load + lgkmcnt(0) stalls (fully exposed at 1 wave/SIMD).
// ---------------------------------------------------------------------------
__global__ __launch_bounds__(64)
void solve_kernel(const float* __restrict__ verts,
                  const float* __restrict__ mesh_V,
                  const float* __restrict__ mesh_N,
                  const int*   __restrict__ mesh_F,
                  const float* __restrict__ ws_d2,
                  const int*   __restrict__ ws_f,
                  float*       __restrict__ out)
{
    const int p = blockIdx.x * 64 + threadIdx.x;

    // merge halves: half 0 wins ties (lower indices) == first occurrence
    const float da = ws_d2[p];
    const float db = ws_d2[kPts + p];
    const int   fa = ws_f[p];
    const int   fb = ws_f[kPts + p];
    const int   f  = (db < da) ? fb : fa;
    out[p] = (float)f;   // fidx as float (exact for idx < 2^24)

    const float qx = verts[p * 3 + 0];
    const float qy = verts[p * 3 + 1];
    const float qz = verts[p * 3 + 2];

    const int i0 = mesh_F[f * 3 + 0];
    const int i1 = mesh_F[f * 3 + 1];
    const int i2 = mesh_F[f * 3 + 2];

    const float V0x = mesh_V[i0*3+0], V0y = mesh_V[i0*3+1], V0z = mesh_V[i0*3+2];
    const float V1x = mesh_V[i1*3+0], V1y = mesh_V[i1*3+1], V1z = mesh_V[i1*3+2];
    const float V2x = mesh_V[i2*3+0], V2y = mesh_V[i2*3+1], V2z = mesh_V[i2*3+2];
    const float N0x = mesh_N[i0*3+0], N0y = mesh_N[i0*3+1], N0z = mesh_N[i0*3+2];
    const float N1x = mesh_N[i1*3+0], N1y = mesh_N[i1*3+1], N1z = mesh_N[i1*3+2];
    const float N2x = mesh_N[i2*3+0], N2y = mesh_N[i2*3+1], N2z = mesh_N[i2*3+2];

    // edge vectors for gradient dots
    const float E0x = V0x - V2x, E0y = V0y - V2y, E0z = V0z - V2z;
    const float E1x = V1x - V2x, E1y = V1y - V2y, E1z = V1z - V2z;
    const float F0x = N0x - N2x, F0y = N0y - N2y, F0z = N0z - N2z;
    const float F1x = N1x - N2x, F1y = N1y - N2y, F1z = N1z - N2z;

    const float tx = qx * SCALE, ty = qy * SCALE, tz = qz * SCALE;
    const float GS = 2.0f / (3.0f * 16384.0f);
    const float B1 = 0.9f,  ONE_M_B1 = 1.0f - 0.9f;
    const float B2 = 0.999f, ONE_M_B2 = 1.0f - 0.999f;

    float vwu = 1.0f / 3.0f, vwv = 1.0f / 3.0f;

    for (int outer = 0; outer < kOuter; ++outer) {
        const float bw0 = (1.0f - vwu) - vwv;
        const float px = ((vwu * V0x + vwv * V1x) + bw0 * V2x);
        const float py = ((vwu * V0y + vwv * V1y) + bw0 * V2y);
        const float pz = ((vwu * V0z + vwv * V1z) + bw0 * V2z);
        const float dx = px - qx, dy = py - qy, dz = pz - qz;
        const float d0 = __builtin_amdgcn_sqrtf((dx * dx + dy * dy) + dz * dz);

        float du = 0.0f, dv = 0.0f, dd = d0;
        float mAu = 0.0f, mAv = 0.0f, mAd = 0.0f;
        float vAu = 0.0f, vAv = 0.0f, vAd = 0.0f;

#pragma unroll
        for (int it = 0; it < kInner; ++it) {
            const float bu = vwu + du;
            const float bv = vwv + dv;
            const float bw = (1.0f - bu) - bv;

            const float cVx = ((bu * V0x + bv * V1x) + bw * V2x) * SCALE;
            const float cVy = ((bu * V0y + bv * V1y) + bw * V2y) * SCALE;
            const float cVz = ((bu * V0z + bv * V1z) + bw * V2z) * SCALE;

            const float nrx = (bu * N0x + bv * N1x) + bw * N2x;
            const float nry = (bu * N0y + bv * N1y) + bw * N2y;
            const float nrz = (bu * N0z + bv * N1z) + bw * N2z;
            const float nn  = (nrx * nrx + nry * nry) + nrz * nrz;
            // 1/max(sqrt(nn),1e-12) == rsq(nn) for the magnitudes here
            const float inv = __builtin_amdgcn_rsqf(nn);
            const float nhx = nrx * inv, nhy = nry * inv, nhz = nrz * inv;
            const float cNx = nhx * SCALE, cNy = nhy * SCALE, cNz = nhz * SCALE;

            const float rx = (cVx + cNx * dd) - tx;
            const float ry = (cVy + cNy * dd) - ty;
            const float rz = (cVz + cNz * dd) - tz;

            const float rv0  = (rx * E0x + ry * E0y) + rz * E0z;
            const float rv1  = (rx * E1x + ry * E1y) + rz * E1z;
            const float rn0  = (rx * F0x + ry * F0y) + rz * F0z;
            const float rn1  = (rx * F1x + ry * F1y) + rz * F1z;
            const float nf0  = (nhx * F0x + nhy * F0y) + nhz * F0z;
            const float nf1  = (nhx * F1x + nhy * F1y) + nhz * F1z;
            const float nr_r = (nhx * rx + nhy * ry) + nhz * rz;

            const float gu = GS * (SCALE * rv0 + (dd * SCALE) * ((rn0 - nr_r * nf0) * inv));
            const float gv = GS * (SCALE * rv1 + (dd * SCALE) * ((rn1 - nr_r * nf1) * inv));
            const float gd = GS * (SCALE * nr_r);

            mAu = B1 * mAu + ONE_M_B1 * gu;
            mAv = B1 * mAv + ONE_M_B1 * gv;
            mAd = B1 * mAd + ONE_M_B1 * gd;
            vAu = B2 * vAu + ONE_M_B2 * (gu * gu);
            vAv = B2 * vAv + ONE_M_B2 * (gv * gv);
            vAd = B2 * vAd + ONE_M_B2 * (gd * gd);

            const float rb1 = kTab.rb1[it];   // compile-time literal (full unroll)
            const float rb2 = kTab.rb2[it];
            // mhat/(sqrt(vhat)+1e-8) ~= mhat * rsq(vhat + 1e-16)
            const float su = __builtin_amdgcn_rsqf(vAu * rb2 + 1e-16f);
            const float sv = __builtin_amdgcn_rsqf(vAv * rb2 + 1e-16f);
            const float sd = __builtin_amdgcn_rsqf(vAd * rb2 + 1e-16f);
            du -= 0.01f * (mAu * rb1) * su;
            dv -= 0.01f * (mAv * rb1) * sv;
            dd -= 0.01f * (mAd * rb1) * sd;
        }
        vwu += du;
        vwv += dv;
    }

    out[kPts + 2 * p + 0] = vwu;
    out[kPts + 2 * p + 1] = vwv;
    out[3 * kPts + p]     = 0.0f;   // outlier_mask = False
}

extern "C" void kernel_launch(void* const* d_in, const int* in_sizes, int n_in,
                              void* d_out, int out_size, void* d_ws, size_t ws_size,
                              hipStream_t stream) {
    const float* verts  = (const float*)d_in[0];
    const float* mesh_V = (const float*)d_in[1];
    const float* mesh_N = (const float*)d_in[2];
    const int*   mesh_F = (const int*)d_in[3];
    float* out = (float*)d_out;

    // workspace layout: centers | d2 candidates | face candidates
    float4* ws_cent = (float4*)d_ws;                                   // kFaces float4
    float*  ws_d2   = (float*)((char*)d_ws + kFaces * sizeof(float4)); // [2][kPts]
    int*    ws_f    = (int*)((char*)ws_d2 + 2 * kPts * sizeof(float)); // [2][kPts]

    hipLaunchKernelGGL(centers_kernel, dim3((kFaces + 255) / 256), dim3(256), 0, stream,
                       mesh_V, mesh_F, ws_cent);
    hipLaunchKernelGGL(knn_kernel,     dim3(2 * kPts / 64), dim3(1024), 0, stream,
                       verts, ws_cent, ws_d2, ws_f);
    hipLaunchKernelGGL(solve_kernel,   dim3(kPts / 64), dim3(64), 0, stream,
                       verts, mesh_V, mesh_N, mesh_F, ws_d2, ws_f, out);
}